// Round 1
// baseline (1278.598 us; speedup 1.0000x reference)
//
#include <hip/hip_runtime.h>

typedef __bf16 bf16;
typedef __bf16 bf16x8 __attribute__((ext_vector_type(8)));
typedef float f32x4 __attribute__((ext_vector_type(4)));

constexpr int kB = 64;
constexpr int kS = 2048;
constexpr int kD = 1024;          // decoder size (N of main GEMM)
constexpr int kM = 1024;          // memory size  (K of main GEMM)
constexpr int kRows = kB * kS;    // 131072

__device__ __forceinline__ void async_copy16(const void* gsrc, void* ldst) {
    __builtin_amdgcn_global_load_lds(
        (const __attribute__((address_space(1))) void*)gsrc,
        (__attribute__((address_space(3))) void*)ldst, 16, 0, 0);
}

__device__ __forceinline__ float fast_tanh(float x) {
    // tanh(x) = 1 - 2/(exp(2x)+1); exp->v_exp_f32, rcp->v_rcp_f32.
    // Saturates correctly: x>>0 -> 1, x<<0 -> -1.
    float e = __expf(2.0f * x);
    return 1.0f - 2.0f * __builtin_amdgcn_rcpf(e + 1.0f);
}

// ---------------------------------------------------------------------------
// P1: WT[d][m] = bf16(W_mem[m][d])  (transpose+cast so B-frag staging is linear)
__global__ __launch_bounds__(256) void wmem_transpose_kernel(
    const float* __restrict__ Wm, bf16* __restrict__ WT) {
    int idx = blockIdx.x * 256 + threadIdx.x;   // 1M threads
    int d = idx >> 10, m = idx & 1023;
    WT[idx] = (bf16)Wm[m * 1024 + d];
}

// ---------------------------------------------------------------------------
// P2: dec_feat[b][d] = sum_m dec[b][m] * W_dec[m][d]   (tiny fp32 GEMM)
__global__ __launch_bounds__(256) void dec_project_kernel(
    const float* __restrict__ dec, const float* __restrict__ Wd,
    float* __restrict__ decf) {
    const int b = blockIdx.x;
    const int d = blockIdx.y * 256 + threadIdx.x;
    const float* drow = dec + b * kD;
    float acc = 0.f;
    #pragma unroll 8
    for (int m = 0; m < kM; ++m)
        acc += drow[m] * Wd[(size_t)m * kD + d];
    decf[b * kD + d] = acc;
}

// ---------------------------------------------------------------------------
// A: fused  E = MB @ W_mem ; partial_score = sum_d tanh(E + decf) * Wv
// 128x128 tile, 16x16x32 bf16 MFMA, 4 waves of 4x4 accumulators.
constexpr int BM = 128, BN = 128, BK = 32, APAD = 40; // APAD: 16B-aligned, conflict-light

__global__ __launch_bounds__(256, 2) void attn_scores_kernel(
    const float* __restrict__ MBank,   // [kRows, kM] fp32
    const bf16*  __restrict__ WT,      // [kD, kM]   bf16 (W_mem transposed)
    const float* __restrict__ decf,    // [kB, kD]
    const float* __restrict__ Wv,      // [kD]
    float* __restrict__ spart)         // [8][kRows]
{
    __shared__ bf16 Atile[BM * APAD];  // rows padded to 40 elems (80B)
    __shared__ bf16 Btile[BN * BK];    // [n][k], stride 32 (global_load_lds layout)
    __shared__ float sred[BM * 2];

    const int tid  = threadIdx.x;
    const int wave = tid >> 6;
    const int lane = tid & 63;
    const int ln   = lane & 15;
    const int quad = lane >> 4;

    const int colTile = blockIdx.x;    // 0..7  (fastest -> co-resident share A via L3)
    const int rowTile = blockIdx.y;    // 0..1023
    const int R0 = rowTile * BM;
    const int C0 = colTile * BN;
    const int batch = rowTile >> 4;    // 128 rows always inside one batch

    const int wr = (wave >> 1) * 64;
    const int wc = (wave & 1) * 64;

    const int arow  = tid >> 1;        // 0..127
    const int akseg = (tid & 1) * 16;  // 0 or 16
    const float* aptr = MBank + (size_t)(R0 + arow) * kM + akseg;

    f32x4 acc[4][4];
    const f32x4 zero = {0.f, 0.f, 0.f, 0.f};
    #pragma unroll
    for (int i = 0; i < 4; ++i)
        #pragma unroll
        for (int j = 0; j < 4; ++j)
            acc[i][j] = zero;

    for (int k0 = 0; k0 < kM; k0 += BK) {
        __syncthreads();
        // ---- stage B (bf16, already transposed): async 16B direct-to-LDS
        #pragma unroll
        for (int j = 0; j < 2; ++j) {
            const int chunk = wave * 2 + j;               // 0..7 (1KB each)
            const int n = chunk * 16 + (lane >> 2);
            async_copy16(WT + (size_t)(C0 + n) * kM + k0 + (lane & 3) * 8,
                         Btile + chunk * 512);
        }
        // ---- stage A: fp32 global -> RTNE bf16 -> LDS (padded rows)
        {
            const float* ap = aptr + k0;
            f32x4 v0 = *(const f32x4*)(ap + 0);
            f32x4 v1 = *(const f32x4*)(ap + 4);
            f32x4 v2 = *(const f32x4*)(ap + 8);
            f32x4 v3 = *(const f32x4*)(ap + 12);
            bf16x8 w0, w1;
            w0[0]=(bf16)v0[0]; w0[1]=(bf16)v0[1]; w0[2]=(bf16)v0[2]; w0[3]=(bf16)v0[3];
            w0[4]=(bf16)v1[0]; w0[5]=(bf16)v1[1]; w0[6]=(bf16)v1[2]; w0[7]=(bf16)v1[3];
            w1[0]=(bf16)v2[0]; w1[1]=(bf16)v2[1]; w1[2]=(bf16)v2[2]; w1[3]=(bf16)v2[3];
            w1[4]=(bf16)v3[0]; w1[5]=(bf16)v3[1]; w1[6]=(bf16)v3[2]; w1[7]=(bf16)v3[3];
            *(bf16x8*)(Atile + arow * APAD + akseg)     = w0;
            *(bf16x8*)(Atile + arow * APAD + akseg + 8) = w1;
        }
        __syncthreads();

        // ---- compute: 8 ds_read_b128 + 16 MFMA per wave
        bf16x8 af[4], bfr[4];
        #pragma unroll
        for (int i = 0; i < 4; ++i)
            af[i] = *(const bf16x8*)(Atile + (wr + i * 16 + ln) * APAD + quad * 8);
        #pragma unroll
        for (int j = 0; j < 4; ++j)
            bfr[j] = *(const bf16x8*)(Btile + (wc + j * 16 + ln) * BK + quad * 8);
        #pragma unroll
        for (int i = 0; i < 4; ++i)
            #pragma unroll
            for (int j = 0; j < 4; ++j)
                acc[i][j] = __builtin_amdgcn_mfma_f32_16x16x32_bf16(
                    af[i], bfr[j], acc[i][j], 0, 0, 0);
    }

    // ---- epilogue: tanh(E+decf)*Wv, reduce over this block's 128 cols
    float wv[4], df[4];
    #pragma unroll
    for (int j = 0; j < 4; ++j) {
        const int d = C0 + wc + j * 16 + ln;
        wv[j] = Wv[d];
        df[j] = decf[batch * kD + d];
    }
    float rp[4][4];
    #pragma unroll
    for (int i = 0; i < 4; ++i) {
        #pragma unroll
        for (int r = 0; r < 4; ++r) {
            float p = 0.f;
            #pragma unroll
            for (int j = 0; j < 4; ++j) {
                float x = acc[i][j][r] + df[j];   // C/D: row=quad*4+r, col=ln
                p += fast_tanh(x) * wv[j];
            }
            #pragma unroll
            for (int off = 1; off < 16; off <<= 1)
                p += __shfl_xor(p, off, 64);      // sum over 16 cols in the quad
            rp[i][r] = p;
        }
    }
    if (ln == 0) {
        #pragma unroll
        for (int i = 0; i < 4; ++i)
            #pragma unroll
            for (int r = 0; r < 4; ++r)
                sred[(wr + i * 16 + quad * 4 + r) * 2 + (wave & 1)] = rp[i][r];
    }
    __syncthreads();
    if (tid < BM)
        spart[(size_t)colTile * kRows + R0 + tid] = sred[tid * 2] + sred[tid * 2 + 1];
}

// ---------------------------------------------------------------------------
// B: softmax over S per batch; writes attn_dist (fp32) to d_out+65536
__global__ __launch_bounds__(256) void softmax_kernel(
    const float* __restrict__ spart, const int* __restrict__ mask,
    float* __restrict__ attn) {
    const int b = blockIdx.x;
    const int tid = threadIdx.x;
    __shared__ float sc[kS];
    __shared__ float redm[4], reds[4];

    float lmax = -INFINITY;
    for (int s = tid; s < kS; s += 256) {
        float v = 0.f;
        #pragma unroll
        for (int t = 0; t < 8; ++t) v += spart[(size_t)t * kRows + b * kS + s];
        if (mask[b * kS + s] == 0) v = -INFINITY;
        sc[s] = v;
        lmax = fmaxf(lmax, v);
    }
    #pragma unroll
    for (int off = 32; off; off >>= 1) lmax = fmaxf(lmax, __shfl_xor(lmax, off, 64));
    if ((tid & 63) == 0) redm[tid >> 6] = lmax;
    __syncthreads();
    const float bmax = fmaxf(fmaxf(redm[0], redm[1]), fmaxf(redm[2], redm[3]));

    float lsum = 0.f;
    for (int s = tid; s < kS; s += 256) {
        float e = __expf(sc[s] - bmax);
        sc[s] = e;
        lsum += e;
    }
    #pragma unroll
    for (int off = 32; off; off >>= 1) lsum += __shfl_xor(lsum, off, 64);
    if ((tid & 63) == 0) reds[tid >> 6] = lsum;
    __syncthreads();
    const float inv = 1.0f / (reds[0] + reds[1] + reds[2] + reds[3]);
    for (int s = tid; s < kS; s += 256) attn[b * kS + s] = sc[s] * inv;
}

// ---------------------------------------------------------------------------
// C1: context partials over s-chunks (memory-bound streaming of memory_bank)
__global__ __launch_bounds__(256) void ctx_partial_kernel(
    const float* __restrict__ MBank, const float* __restrict__ attn,
    float* __restrict__ cpart) {
    const int b  = blockIdx.x;   // 64
    const int sc = blockIdx.y;   // 16 chunks of 128 s
    const int m4 = threadIdx.x * 4;
    const float* base = MBank + ((size_t)b * kS + sc * 128) * kM + m4;
    const float* ap = attn + b * kS + sc * 128;
    f32x4 acc = {0.f, 0.f, 0.f, 0.f};
    #pragma unroll 4
    for (int s = 0; s < 128; ++s) {
        const float a = ap[s];
        f32x4 v = *(const f32x4*)(base + (size_t)s * kM);
        acc[0] += a * v[0]; acc[1] += a * v[1];
        acc[2] += a * v[2]; acc[3] += a * v[3];
    }
    *(f32x4*)&cpart[((size_t)(b * 16 + sc)) * kM + m4] = acc;
}

// C2: reduce the 16 s-chunk partials -> context
__global__ __launch_bounds__(256) void ctx_reduce_kernel(
    const float* __restrict__ cpart, float* __restrict__ out) {
    const int idx = blockIdx.x * 256 + threadIdx.x;  // 65536
    const int b = idx >> 10, m = idx & 1023;
    float v = 0.f;
    #pragma unroll
    for (int c = 0; c < 16; ++c) v += cpart[(size_t)((b * 16 + c) << 10) + m];
    out[idx] = v;
}

// ---------------------------------------------------------------------------
extern "C" void kernel_launch(void* const* d_in, const int* in_sizes, int n_in,
                              void* d_out, int out_size, void* d_ws, size_t ws_size,
                              hipStream_t stream) {
    const float* dec   = (const float*)d_in[0];   // [64,1024]
    const float* MBank = (const float*)d_in[1];   // [64,2048,1024]
    const int*   mask  = (const int*)d_in[2];     // [64,2048]
    const float* Wv    = (const float*)d_in[3];   // [1024]
    const float* Wdec  = (const float*)d_in[4];   // [1024,1024]
    const float* Wmem  = (const float*)d_in[5];   // [1024,1024]

    float* out_ctx  = (float*)d_out;              // 65536 floats
    float* out_attn = (float*)d_out + kB * kD;    // 131072 floats

    char* ws = (char*)d_ws;
    bf16*  WT    = (bf16*)ws;                                   // 2 MB
    float* decf  = (float*)(ws + (1 << 21));                    // 256 KB
    float* spart = (float*)(ws + (1 << 21) + (1 << 18));        // 4 MB
    float* cpart = (float*)(ws + (1 << 21) + (1 << 18) + (1 << 22)); // 4 MB

    wmem_transpose_kernel<<<4096, 256, 0, stream>>>(Wmem, WT);
    dec_project_kernel<<<dim3(64, 4), 256, 0, stream>>>(dec, Wdec, decf);
    attn_scores_kernel<<<dim3(8, 1024), 256, 0, stream>>>(MBank, WT, decf, Wv, spart);
    softmax_kernel<<<64, 256, 0, stream>>>(spart, mask, out_attn);
    ctx_partial_kernel<<<dim3(64, 16), 256, 0, stream>>>(MBank, out_attn, cpart);
    ctx_reduce_kernel<<<256, 256, 0, stream>>>(cpart, out_ctx);
}